// Round 4
// baseline (134.447 us; speedup 1.0000x reference)
//
#include <hip/hip_runtime.h>
#include <math.h>

// QGRUCell — Round 11: cut LLC A-duplication 8x -> 4x.
// Theory: all R7-R10 structures ~44us because A (16MB ws region) is re-read
// by every n-group through the Infinity Cache (8x dup = 128MB LLC reads
// ~= 3TB/s ~= the wall). BM=128 x BN=128, 512-thread blocks (8 waves 2m x 4n),
// grid 256 = 64 m-panels x 4 n-groups = 1 block/CU (LDS 144KB forces it).
// A-dup -> 4x (64MB). W slice per XCD = 768KB, L2-resident (n = bid&3,
// XCD = bid&7 => fixed n-group per XCD). A direct-to-reg (4 n-waves share
// chunks -> L1 dedup), W via global_load_lds into 3 x 48KB slabs, 2-step-
// ahead counted vmcnt(28), full unroll, merged r/i acc, setprio.
// ws layout unchanged: 512-f16 chunks, A: arr*8192+M32*32+K16,
// W: 16384+(g*16+N32)*32+K16; chunk pos(row,k)=(k>>3&1)*256+row*8+(k&7).

typedef _Float16 f16x8  __attribute__((ext_vector_type(8)));
typedef _Float16 f16x4  __attribute__((ext_vector_type(4)));
typedef __bf16   bf16x8 __attribute__((ext_vector_type(8)));
typedef float    f32x16 __attribute__((ext_vector_type(16)));

namespace {

constexpr int Bsz = 8192, Ksz = 512, Hsz = 512;
constexpr int BM = 64, BN = 64;          // fallback kernel tile

constexpr unsigned WCH0    = 16384u;
constexpr unsigned NCHUNK  = 16384u + 3072u;          // 19456
constexpr unsigned WS_F16  = NCHUNK * 512u;           // 9,961,472 f16
constexpr size_t   WS_NEED = (size_t)WS_F16 * 2;      // 19,922,944 B

constexpr int SLAB2 = 24576;             // f16 per W slab (48 KB), 3 slabs

__device__ __forceinline__ float qround(float x, float s, float invs) {
    return floorf(x * s + 0.5f) * invs;
}

__device__ __forceinline__ float qsigmoid_dev(float x) {
    float iq = floorf(x * 134217728.0f + 0.5f);
    iq = fminf(fmaxf(iq, -2147483648.0f), 2147483648.0f);
    float e = __expf(-iq * 7.450580596923828125e-9f);
    float s = __builtin_amdgcn_rcpf(1.0f + e);
    float q31 = floorf(s * 2147483648.0f + 0.5f);
    float q15 = floorf(q31 * 1.52587890625e-5f + 0.5f);
    return q15 * 3.0517578125e-5f;
}

__device__ __forceinline__ float qtanh_dev(float x) {
    float iq = floorf(x * 134217728.0f + 0.5f);
    iq = fminf(fmaxf(iq, -2147483648.0f), 2147483648.0f);
    float z = iq * 7.450580596923828125e-9f;
    float e = __expf(2.0f * z);
    float t = 1.0f - 2.0f * __builtin_amdgcn_rcpf(e + 1.0f);
    float q31 = floorf(t * 2147483648.0f + 0.5f);
    float q15 = floorf(q31 * 1.52587890625e-5f + 0.5f);
    return q15 * 3.0517578125e-5f;
}

__device__ __forceinline__ void dma16(const void* g, void* l) {
    __builtin_amdgcn_global_load_lds(
        (const __attribute__((address_space(1))) unsigned int*)g,
        (__attribute__((address_space(3))) unsigned int*)l, 16, 0, 0);
}

__device__ __forceinline__ void split2(float a, float b, unsigned& hi, unsigned& lo) {
    unsigned ua = __float_as_uint(a); ua += 0x7fffu + ((ua >> 16) & 1u);
    unsigned ub = __float_as_uint(b); ub += 0x7fffu + ((ub >> 16) & 1u);
    hi = (ua >> 16) | (ub & 0xffff0000u);
    float ra = a - __uint_as_float(ua & 0xffff0000u);
    float rb = b - __uint_as_float(ub & 0xffff0000u);
    unsigned va = __float_as_uint(ra); va += 0x7fffu + ((va >> 16) & 1u);
    unsigned vb = __float_as_uint(rb); vb += 0x7fffu + ((vb >> 16) & 1u);
    lo = (va >> 16) | (vb & 0xffff0000u);
}

} // namespace

// ---------------- pre-pass: LDS-tile-transpose fp32 -> f16 chunks ----------
__global__ __launch_bounds__(256) void cvt_lds_f16(
    const float* __restrict__ x, const float* __restrict__ h,
    const float* __restrict__ wih, const float* __restrict__ whh,
    _Float16* __restrict__ ws)
{
    __shared__ __align__(16) _Float16 lt[8192];   // 16 KB

    const int b2  = blockIdx.x;
    const int b   = b2 >> 1;
    const int kha = b2 & 1;
    const int tid = threadIdx.x;

    const float* src;      // base of the 32-row group (row-major, stride 512)
    unsigned chbase;       // first chunk index of this group
    if (b < 512) {                         // A: x (arr0), h (arr1)
        const int arr = b >> 8, M32 = b & 255;
        src = (arr ? h : x) + (size_t)M32 * 32u * 512u;
        chbase = (unsigned)arr * 8192u + (unsigned)M32 * 32u;
    } else {                               // W: gate g, col-group N32
        const int w = b - 512;             // 0..95
        const int g = w >> 4, N32 = w & 15;
        const int rowLocal = (g % 3) * 512 + N32 * 32;
        src = (g < 3 ? wih : whh) + (size_t)rowLocal * 512u;
        chbase = WCH0 + (unsigned)((g * 16 + N32) * 32);
    }
    src += kha * 256;                      // K-half column offset

    // Phase 1: 8 reps x 256 threads covering 32 rows x 64 float4s
#pragma unroll
    for (int rep = 0; rep < 8; ++rep) {
        const int idx = rep * 256 + tid;       // 0..2047
        const int row = idx >> 6;              // 0..31
        const int q   = idx & 63;              // local float4 col
        const float4 v = *(const float4*)(src + (size_t)row * 512 + q * 4);
        const int K16l = q >> 2;               // 0..15
        const int kh   = (q >> 1) & 1;
        const int half = (q & 1) * 4;
        const int rsw  = (row + (q >> 1)) & 31;
        f16x4 o;
        o[0] = (_Float16)v.x; o[1] = (_Float16)v.y;
        o[2] = (_Float16)v.z; o[3] = (_Float16)v.w;
        *(f16x4*)&lt[K16l * 512 + kh * 256 + rsw * 8 + half] = o;
    }
    __syncthreads();

    // Phase 2: wave w writes chunks K16l = w*4 .. w*4+3
    const int wid = tid >> 6, lane = tid & 63;
    const int kh  = lane >> 5, row = lane & 31;
#pragma unroll
    for (int cc = 0; cc < 4; ++cc) {
        const int K16l = wid * 4 + cc;
        const int rsw  = (row + 2 * K16l + kh) & 31;
        const f16x8 o = *(const f16x8*)&lt[K16l * 512 + kh * 256 + rsw * 8];
        *(f16x8*)(ws + (size_t)(chbase + (unsigned)(kha * 16 + K16l)) * 512u
                      + lane * 8) = o;
    }
}

// ---------------- main: BM=128 x BN=128, 4x A-dup, deep pipeline -----------
__global__ __launch_bounds__(512, 2) void qgru_f16_dma6(
    const _Float16* __restrict__ ws, const float* __restrict__ hid,
    const float* __restrict__ bih, const float* __restrict__ bhh,
    float* __restrict__ out)
{
    __shared__ __align__(16) _Float16 lds[3 * SLAB2];   // 144 KB -> 1 block/CU

    const int t = threadIdx.x, lane = t & 63, wid = t >> 6;   // wid 0..7
    const int mt = wid >> 2, nt = wid & 3;   // 2m x 4n wave grid (64x32 tiles)

    const int bid = blockIdx.x;
    const int n0  = (bid & 3) * 128;       // n-group; XCD=bid&7 => fixed per XCD
    const int m0  = (bid >> 2) * 128;      // 64 m-panels of 128 rows

    // W chunks: 48/step, 6 per wave. gi = ((g*4+n32)*2+ks2); wave wid owns
    // gi = wid*6 .. wid*6+5.
    unsigned goffW[6];
    int      ldstW[6];
#pragma unroll
    for (int c = 0; c < 6; ++c) {
        const int gi = wid * 6 + c;
        const int g = gi >> 3, n32 = (gi >> 1) & 3, ks2 = gi & 1;
        const unsigned ch = WCH0
            + (unsigned)((g * 16 + (n0 >> 5) + n32) * 32) + (unsigned)ks2;
        goffW[c] = ch * 1024u + (unsigned)lane * 16u;
        ldstW[c] = gi * 512;
    }

    // A fragments: 8/step per wave (i = ks2*4 + arr*2 + mf); chunk layout IS
    // the fragment layout: lane l's frag = chunk bytes [16l, 16l+16).
    // 4 n-waves with the same mt load identical chunks -> L1 dedups.
    unsigned offA[8];
#pragma unroll
    for (int i = 0; i < 8; ++i) {
        const int ks2 = i >> 2, arr = (i >> 1) & 1, mf = i & 1;
        const unsigned ch = (unsigned)arr * 8192u
            + (unsigned)((m0 >> 5) + mt * 2 + mf) * 32u + (unsigned)ks2;
        offA[i] = ch * 1024u + (unsigned)lane * 16u;
    }

    // acc chains: 0 = r (gi_r+gh_r merged), 1 = i (merged), 2 = gi_n, 3 = gh_n
    f32x16 acc[4][2];
#pragma unroll
    for (int cid = 0; cid < 4; ++cid)
#pragma unroll
        for (int mf = 0; mf < 2; ++mf)
#pragma unroll
            for (int i = 0; i < 16; ++i) acc[cid][mf][i] = 0.0f;

    const char* wsb = (const char*)ws;
    const int lr = lane & 31, lk8 = (lane >> 5) * 8;

    f16x8 aS[3][8];   // 3-deep A register sets; all indices compile-time

    // prologue: batches 0 and 1 (14 VMEM ops/wave each, stay in flight)
#pragma unroll
    for (int b = 0; b < 2; ++b) {
        const unsigned kb = (unsigned)b * 2048u;
#pragma unroll
        for (int i = 0; i < 8; ++i)
            aS[b][i] = *(const f16x8*)(wsb + offA[i] + kb);
#pragma unroll
        for (int c = 0; c < 6; ++c)
            dma16(wsb + goffW[c] + kb, &lds[b * SLAB2 + ldstW[c]]);
    }

#pragma unroll
    for (int step = 0; step < 16; ++step) {
        const int cur = step % 3;

        if (step < 14) {
            const int nxt = (step + 2) % 3;
            const unsigned kb = (unsigned)(step + 2) * 2048u;
#pragma unroll
            for (int i = 0; i < 8; ++i)
                aS[nxt][i] = *(const f16x8*)(wsb + offA[i] + kb);
#pragma unroll
            for (int c = 0; c < 6; ++c)
                dma16(wsb + goffW[c] + kb, &lds[nxt * SLAB2 + ldstW[c]]);
            asm volatile("s_waitcnt vmcnt(28)" ::: "memory");  // batch(step) done
        } else if (step == 14) {
            asm volatile("s_waitcnt vmcnt(14)" ::: "memory");
        } else {
            asm volatile("s_waitcnt vmcnt(0)" ::: "memory");
        }
        __builtin_amdgcn_s_barrier();          // slab[cur] visible to all waves
        __builtin_amdgcn_s_setprio(1);

#pragma unroll
        for (int ks2 = 0; ks2 < 2; ++ks2) {
            const int base = cur * SLAB2 + lk8 * 32 + lr * 8;
#pragma unroll
            for (int g = 0; g < 6; ++g) {
                const f16x8 bv = *(const f16x8*)
                    &lds[base + (((g * 4 + nt) * 2 + ks2) * 512)];
                const int cid = (g < 3) ? g : (g == 5 ? 3 : g - 3);
                const int ab  = ks2 * 4 + ((g < 3) ? 0 : 2);
                acc[cid][0] = __builtin_amdgcn_mfma_f32_32x32x16_f16(
                                  aS[cur][ab + 0], bv, acc[cid][0], 0, 0, 0);
                acc[cid][1] = __builtin_amdgcn_mfma_f32_32x32x16_f16(
                                  aS[cur][ab + 1], bv, acc[cid][1], 0, 0, 0);
            }
        }

        __builtin_amdgcn_s_setprio(0);
        asm volatile("" ::: "memory");
        __builtin_amdgcn_s_barrier();          // all done reading slab[cur]
    }

    constexpr float S14 = 16384.0f,     I14 = 1.0f / 16384.0f;
    constexpr float S15 = 32768.0f,     I15 = 1.0f / 32768.0f;

    const int lh = lane >> 5, l32 = lane & 31;
    const int n = n0 + nt * 32 + l32;
    const float brc = bih[n] + bhh[n];                 // merged r bias
    const float bic = bih[n + 512] + bhh[n + 512];     // merged i bias
    const float bnn = bih[n + 1024];
    const float cnn = bhh[n + 1024];

#pragma unroll
    for (int mf = 0; mf < 2; ++mf) {
#pragma unroll
        for (int r = 0; r < 16; ++r) {
            const int row = (r & 3) + 8 * (r >> 2) + 4 * lh;
            const int m   = m0 + mt * 64 + mf * 32 + row;
            const float hv = hid[(size_t)m * Hsz + n];
            const float rg  = qsigmoid_dev(qround(acc[0][mf][r] + brc, S14, I14));
            const float ig  = qsigmoid_dev(qround(acc[1][mf][r] + bic, S14, I14));
            const float gin = qround(acc[2][mf][r] + bnn, S14, I14);
            const float ghn = qround(acc[3][mf][r] + cnn, S14, I14);
            const float rh  = qround(rg * ghn, S15, I15);
            const float ng  = qtanh_dev(rh + gin);
            const float nh  = qround(hv, S15, I15);
            out[(size_t)m * Hsz + n] = ng + ig * (nh - ng);
        }
    }
}

// ---------------- fallback: bf16x3 (used only if ws too small) -------------
__global__ __launch_bounds__(256, 2) void qgru_mfma_bf16x3(
    const float* __restrict__ x, const float* __restrict__ hid,
    const float* __restrict__ wih, const float* __restrict__ whh,
    const float* __restrict__ bih, const float* __restrict__ bhh,
    float* __restrict__ out)
{
    __shared__ __align__(16) unsigned short lds[16384];

    const int t = threadIdx.x, lane = t & 63, wid = t >> 6;
    const int mt = wid >> 1, nt = wid & 1;
    const int m0 = blockIdx.x * BM, n0 = blockIdx.y * BN;
    const int s_r = t >> 2, s_k = (t & 3) << 2;
    const int s_kh = s_k >> 3, s_j = s_k & 7, s_rt = s_r >> 5, s_r32 = s_r & 31;

    const float* gA[2];
    gA[0] = x   + (size_t)(m0 + s_r) * Ksz + s_k;
    gA[1] = hid + (size_t)(m0 + s_r) * Ksz + s_k;
    const float* gW[6];
#pragma unroll
    for (int g = 0; g < 3; ++g) {
        gW[g]     = wih + (size_t)(g * Hsz + n0 + s_r) * Ksz + s_k;
        gW[g + 3] = whh + (size_t)(g * Hsz + n0 + s_r) * Ksz + s_k;
    }
    const int lh = lane >> 5, l32 = lane & 31;

    f32x16 acc[6];
#pragma unroll
    for (int g = 0; g < 6; ++g)
#pragma unroll
        for (int i = 0; i < 16; ++i) acc[g][i] = 0.0f;

    float4 vA[2], vW[6];
#pragma unroll
    for (int tt = 0; tt < 2; ++tt) vA[tt] = *(const float4*)gA[tt];
#pragma unroll
    for (int g = 0; g < 6; ++g)    vW[g]  = *(const float4*)gW[g];

    for (int k0 = 0; k0 < Ksz; k0 += 16) {
        __syncthreads();
#pragma unroll
        for (int tt = 0; tt < 2; ++tt) {
            unsigned h0, h1, l0, l1;
            split2(vA[tt].x, vA[tt].y, h0, l0);
            split2(vA[tt].z, vA[tt].w, h1, l1);
            unsigned bH = ((((tt*2+0)*2+s_rt)*2+s_kh)*32+s_r32)*8 + s_j;
            unsigned bL = ((((tt*2+1)*2+s_rt)*2+s_kh)*32+s_r32)*8 + s_j;
            *reinterpret_cast<uint2*>(&lds[bH]) = make_uint2(h0, h1);
            *reinterpret_cast<uint2*>(&lds[bL]) = make_uint2(l0, l1);
        }
#pragma unroll
        for (int g = 0; g < 6; ++g) {
            unsigned h0, h1, l0, l1;
            split2(vW[g].x, vW[g].y, h0, l0);
            split2(vW[g].z, vW[g].w, h1, l1);
            unsigned bH = 4096u + ((((g*2+0)*2+s_rt)*2+s_kh)*32+s_r32)*8 + s_j;
            unsigned bL = 4096u + ((((g*2+1)*2+s_rt)*2+s_kh)*32+s_r32)*8 + s_j;
            *reinterpret_cast<uint2*>(&lds[bH]) = make_uint2(h0, h1);
            *reinterpret_cast<uint2*>(&lds[bL]) = make_uint2(l0, l1);
        }
        __syncthreads();
        const int kn = (k0 + 16 < Ksz) ? (k0 + 16) : 0;
#pragma unroll
        for (int tt = 0; tt < 2; ++tt) vA[tt] = *(const float4*)(gA[tt] + kn);
#pragma unroll
        for (int g = 0; g < 6; ++g)    vW[g]  = *(const float4*)(gW[g] + kn);

        const bf16x8 ax_hi = *reinterpret_cast<const bf16x8*>(&lds[((((0)*2+mt)*2+lh)*32+l32)*8]);
        const bf16x8 ax_lo = *reinterpret_cast<const bf16x8*>(&lds[((((1)*2+mt)*2+lh)*32+l32)*8]);
        const bf16x8 ah_hi = *reinterpret_cast<const bf16x8*>(&lds[((((2)*2+mt)*2+lh)*32+l32)*8]);
        const bf16x8 ah_lo = *reinterpret_cast<const bf16x8*>(&lds[((((3)*2+mt)*2+lh)*32+l32)*8]);
#pragma unroll
        for (int g = 0; g < 6; ++g) {
            const bf16x8 b_hi = *reinterpret_cast<const bf16x8*>(&lds[4096u + ((((g*2+0)*2+nt)*2+lh)*32+l32)*8]);
            const bf16x8 b_lo = *reinterpret_cast<const bf16x8*>(&lds[4096u + ((((g*2+1)*2+nt)*2+lh)*32+l32)*8]);
            const bf16x8 a_hi = (g < 3) ? ax_hi : ah_hi;
            const bf16x8 a_lo = (g < 3) ? ax_lo : ah_lo;
            acc[g] = __builtin_amdgcn_mfma_f32_32x32x16_bf16(a_hi, b_hi, acc[g], 0, 0, 0);
            acc[g] = __builtin_amdgcn_mfma_f32_32x32x16_bf16(a_hi, b_lo, acc[g], 0, 0, 0);
            acc[g] = __builtin_amdgcn_mfma_f32_32x32x16_bf16(a_lo, b_hi, acc[g], 0, 0, 0);
        }
    }

    constexpr float S14 = 16384.0f,     I14 = 1.0f / 16384.0f;
    constexpr float S15 = 32768.0f,     I15 = 1.0f / 32768.0f;
    constexpr float S27 = 134217728.0f, I27 = 1.0f / 134217728.0f;
    const int n = n0 + nt * 32 + l32;
    const float br = bih[n], bi = bih[n + 512], bn = bih[n + 1024];
    const float cr = bhh[n], ci = bhh[n + 512], cn = bhh[n + 1024];
#pragma unroll
    for (int r = 0; r < 16; ++r) {
        const int row = (r & 3) + 8 * (r >> 2) + 4 * lh;
        const int m   = m0 + mt * 32 + row;
        const float hv = hid[(size_t)m * Hsz + n];
        float gir = qround(acc[0][r] + br, S14, I14);
        float gii = qround(acc[1][r] + bi, S14, I14);
        float gin = qround(acc[2][r] + bn, S14, I14);
        float ghr = qround(acc[3][r] + cr, S14, I14);
        float ghi = qround(acc[4][r] + ci, S14, I14);
        float ghn = qround(acc[5][r] + cn, S14, I14);
        float resetg = qsigmoid_dev(gir + ghr);
        float inputg = qsigmoid_dev(gii + ghi);
        float hn  = qround(ghn, S27, I27);
        float rh  = qround(resetg * hn, S15, I15);
        float newg = qtanh_dev(rh + gin);
        float nh  = qround(hv, S15, I15);
        out[(size_t)m * Hsz + n] = newg + inputg * (nh - newg);
    }
}

extern "C" void kernel_launch(void* const* d_in, const int* in_sizes, int n_in,
                              void* d_out, int out_size, void* d_ws, size_t ws_size,
                              hipStream_t stream) {
    const float* x   = (const float*)d_in[0];
    const float* hid = (const float*)d_in[1];
    const float* wih = (const float*)d_in[2];
    const float* whh = (const float*)d_in[3];
    const float* bih = (const float*)d_in[4];
    const float* bhh = (const float*)d_in[5];
    float* out = (float*)d_out;

    if (ws_size >= WS_NEED) {
        cvt_lds_f16<<<1216, 256, 0, stream>>>(
            x, hid, wih, whh, (_Float16*)d_ws);
        qgru_f16_dma6<<<256, 512, 0, stream>>>(
            (const _Float16*)d_ws, hid, bih, bhh, out);
    } else {
        dim3 grid(Bsz / BM, Hsz / BN);
        qgru_mfma_bf16x3<<<grid, dim3(256), 0, stream>>>(
            x, hid, wih, whh, bih, bhh, out);
    }
}

// Round 6
// 134.102 us; speedup vs baseline: 1.0026x; 1.0026x over previous
//
#include <hip/hip_runtime.h>
#include <math.h>

// QGRUCell — Round 12b: 8-phase interleaved schedule (T3+T4+T5 port).
// (Resubmission of R12 — round 5's bench died on container acquire, not on
// the kernel; audit found no hang/fault risk. Experiment still unrun.)
// All 2-phase variants (R7-R11) pinned at ~45us = the m233 2-phase ceiling
// (575TF effective ~= 607TF documented). This round ports the verified
// 8-phase template: per K-tile(64) 8 phases, each {3 B ds_reads + 1 A-load
// (+ phase7: 6 W-dma + counted vmcnt(6)) ; barrier ; lgkmcnt(0) ; setprio1 ;
// 3 MFMA ; setprio0 ; barrier}. Issue order A...A,W...W so vmcnt(6) keeps
// exactly the next-next W batch in flight (never drain-0 mid-loop).
// Geometry: 512thr = 8 waves (4m x 2n), wave tile 32x32, BM=128 BN=64,
// grid 512, K-tile 64, 3 W-slabs x 48KB = 144KB (1 block/CU).
// acc = 4 merged chains (r,i merged across gi/gh) = 64 regs; A 2-deep 64.
// ws layout unchanged: 512-f16 chunks, A: arr*8192+M32*32+K16,
// W: 16384+(g*16+N32)*32+K16; chunk pos(row,k)=(k>>3&1)*256+row*8+(k&7).

typedef _Float16 f16x8  __attribute__((ext_vector_type(8)));
typedef _Float16 f16x4  __attribute__((ext_vector_type(4)));
typedef __bf16   bf16x8 __attribute__((ext_vector_type(8)));
typedef float    f32x16 __attribute__((ext_vector_type(16)));

namespace {

constexpr int Bsz = 8192, Ksz = 512, Hsz = 512;
constexpr int BM = 64, BN = 64;          // fallback kernel tile

constexpr unsigned WCH0    = 16384u;
constexpr unsigned NCHUNK  = 16384u + 3072u;          // 19456
constexpr unsigned WS_F16  = NCHUNK * 512u;           // 9,961,472 f16
constexpr size_t   WS_NEED = (size_t)WS_F16 * 2;      // 19,922,944 B

constexpr int SLABF = 24576;             // f16 per W slab (48 KB), 3 slabs

__device__ __forceinline__ float qround(float x, float s, float invs) {
    return floorf(x * s + 0.5f) * invs;
}

__device__ __forceinline__ float qsigmoid_dev(float x) {
    float iq = floorf(x * 134217728.0f + 0.5f);
    iq = fminf(fmaxf(iq, -2147483648.0f), 2147483648.0f);
    float e = __expf(-iq * 7.450580596923828125e-9f);
    float s = __builtin_amdgcn_rcpf(1.0f + e);
    float q31 = floorf(s * 2147483648.0f + 0.5f);
    float q15 = floorf(q31 * 1.52587890625e-5f + 0.5f);
    return q15 * 3.0517578125e-5f;
}

__device__ __forceinline__ float qtanh_dev(float x) {
    float iq = floorf(x * 134217728.0f + 0.5f);
    iq = fminf(fmaxf(iq, -2147483648.0f), 2147483648.0f);
    float z = iq * 7.450580596923828125e-9f;
    float e = __expf(2.0f * z);
    float t = 1.0f - 2.0f * __builtin_amdgcn_rcpf(e + 1.0f);
    float q31 = floorf(t * 2147483648.0f + 0.5f);
    float q15 = floorf(q31 * 1.52587890625e-5f + 0.5f);
    return q15 * 3.0517578125e-5f;
}

__device__ __forceinline__ void dma16(const void* g, void* l) {
    __builtin_amdgcn_global_load_lds(
        (const __attribute__((address_space(1))) unsigned int*)g,
        (__attribute__((address_space(3))) unsigned int*)l, 16, 0, 0);
}

__device__ __forceinline__ void split2(float a, float b, unsigned& hi, unsigned& lo) {
    unsigned ua = __float_as_uint(a); ua += 0x7fffu + ((ua >> 16) & 1u);
    unsigned ub = __float_as_uint(b); ub += 0x7fffu + ((ub >> 16) & 1u);
    hi = (ua >> 16) | (ub & 0xffff0000u);
    float ra = a - __uint_as_float(ua & 0xffff0000u);
    float rb = b - __uint_as_float(ub & 0xffff0000u);
    unsigned va = __float_as_uint(ra); va += 0x7fffu + ((va >> 16) & 1u);
    unsigned vb = __float_as_uint(rb); vb += 0x7fffu + ((vb >> 16) & 1u);
    lo = (va >> 16) | (vb & 0xffff0000u);
}

} // namespace

// ---------------- pre-pass: LDS-tile-transpose fp32 -> f16 chunks ----------
__global__ __launch_bounds__(256) void cvt_lds_f16(
    const float* __restrict__ x, const float* __restrict__ h,
    const float* __restrict__ wih, const float* __restrict__ whh,
    _Float16* __restrict__ ws)
{
    __shared__ __align__(16) _Float16 lt[8192];   // 16 KB

    const int b2  = blockIdx.x;
    const int b   = b2 >> 1;
    const int kha = b2 & 1;
    const int tid = threadIdx.x;

    const float* src;      // base of the 32-row group (row-major, stride 512)
    unsigned chbase;       // first chunk index of this group
    if (b < 512) {                         // A: x (arr0), h (arr1)
        const int arr = b >> 8, M32 = b & 255;
        src = (arr ? h : x) + (size_t)M32 * 32u * 512u;
        chbase = (unsigned)arr * 8192u + (unsigned)M32 * 32u;
    } else {                               // W: gate g, col-group N32
        const int w = b - 512;             // 0..95
        const int g = w >> 4, N32 = w & 15;
        const int rowLocal = (g % 3) * 512 + N32 * 32;
        src = (g < 3 ? wih : whh) + (size_t)rowLocal * 512u;
        chbase = WCH0 + (unsigned)((g * 16 + N32) * 32);
    }
    src += kha * 256;                      // K-half column offset

    // Phase 1: 8 reps x 256 threads covering 32 rows x 64 float4s
#pragma unroll
    for (int rep = 0; rep < 8; ++rep) {
        const int idx = rep * 256 + tid;       // 0..2047
        const int row = idx >> 6;              // 0..31
        const int q   = idx & 63;              // local float4 col
        const float4 v = *(const float4*)(src + (size_t)row * 512 + q * 4);
        const int K16l = q >> 2;               // 0..15
        const int kh   = (q >> 1) & 1;
        const int half = (q & 1) * 4;
        const int rsw  = (row + (q >> 1)) & 31;
        f16x4 o;
        o[0] = (_Float16)v.x; o[1] = (_Float16)v.y;
        o[2] = (_Float16)v.z; o[3] = (_Float16)v.w;
        *(f16x4*)&lt[K16l * 512 + kh * 256 + rsw * 8 + half] = o;
    }
    __syncthreads();

    // Phase 2: wave w writes chunks K16l = w*4 .. w*4+3
    const int wid = tid >> 6, lane = tid & 63;
    const int kh  = lane >> 5, row = lane & 31;
#pragma unroll
    for (int cc = 0; cc < 4; ++cc) {
        const int K16l = wid * 4 + cc;
        const int rsw  = (row + 2 * K16l + kh) & 31;
        const f16x8 o = *(const f16x8*)&lt[K16l * 512 + kh * 256 + rsw * 8];
        *(f16x8*)(ws + (size_t)(chbase + (unsigned)(kha * 16 + K16l)) * 512u
                      + lane * 8) = o;
    }
}

// ---------------- main: 8-phase interleaved schedule -----------------------
__global__ __launch_bounds__(512, 2) void qgru_f16_p8(
    const _Float16* __restrict__ ws, const float* __restrict__ hid,
    const float* __restrict__ bih, const float* __restrict__ bhh,
    float* __restrict__ out)
{
    __shared__ __align__(16) _Float16 lds[3 * SLABF];   // 144 KB -> 1 block/CU

    const int t512 = threadIdx.x, lane = t512 & 63, wid = t512 >> 6; // wid 0..7
    const int mt = wid >> 1, nt = wid & 1;     // 4m x 2n, wave tile 32x32

    const int bid = blockIdx.x;
    const int n0  = (bid & 7) * 64;        // 8 n-groups; XCD=bid%8 pins W slice
    const int m0  = (bid >> 3) * 128;      // 64 m-panels of 128 rows

    // W chunks per K-tile: 48 (g x n32 x k16), 6 per wave.
    // gi = g*8 + n32*4 + k16 ; wave wid owns gi = wid*6 .. wid*6+5.
    unsigned goffW[6];
    int      ldstW[6];
#pragma unroll
    for (int c = 0; c < 6; ++c) {
        const int gi = wid * 6 + c;
        const int g = gi >> 3, n32 = (gi >> 2) & 1, k16 = gi & 3;
        const unsigned ch = WCH0
            + (unsigned)((g * 16 + (n0 >> 5) + n32) * 32) + (unsigned)k16;
        goffW[c] = ch * 1024u + (unsigned)lane * 16u;
        ldstW[c] = gi * 512;
    }

    // A fragment bases: frag idx within tile i = k16*2 + arr  (i == phase).
    unsigned offAb[2];
#pragma unroll
    for (int arr = 0; arr < 2; ++arr) {
        const unsigned ch = (unsigned)arr * 8192u
            + (unsigned)(((m0 >> 5) + mt) * 32);
        offAb[arr] = ch * 1024u + (unsigned)lane * 16u;
    }

    // acc chains: 0 = r (gi_r+gh_r merged), 1 = i (merged), 2 = gi_n, 3 = gh_n
    f32x16 acc[4];
#pragma unroll
    for (int cid = 0; cid < 4; ++cid)
#pragma unroll
        for (int i = 0; i < 16; ++i) acc[cid][i] = 0.0f;

    const char* wsb = (const char*)ws;

    f16x8 aS[2][8];   // 2-deep A sets; loop fully unrolled -> static indices

    // ---- prologue: A(0) x8, then W(0) x6, W(1) x6 (strict A-first order) --
#pragma unroll
    for (int i = 0; i < 8; ++i)
        aS[0][i] = *(const f16x8*)(wsb + offAb[i & 1] + (unsigned)((i >> 1) * 1024));
#pragma unroll
    for (int b = 0; b < 2; ++b)
#pragma unroll
        for (int c = 0; c < 6; ++c)
            dma16(wsb + goffW[c] + (unsigned)(b * 4096),
                  &lds[b * SLABF + ldstW[c]]);
    asm volatile("s_waitcnt vmcnt(6)" ::: "memory");   // A(0)+W(0) done, W(1) in flight
    __builtin_amdgcn_s_barrier();

#pragma unroll
    for (int t = 0; t < 8; ++t) {
        const int cur  = t % 3;
        const int nxtw = (t + 2) % 3;
#pragma unroll
        for (int ph = 0; ph < 8; ++ph) {
            const int k16 = ph >> 1, h = ph & 1;
            const int rbase = cur * SLABF + k16 * 512 + lane * 8;
            // 3 B fragments (gates 3h..3h+2, this wave's nt column)
            const f16x8 b0 = *(const f16x8*)&lds[rbase + (((3*h+0)*2 + nt) * 2048)];
            const f16x8 b1 = *(const f16x8*)&lds[rbase + (((3*h+1)*2 + nt) * 2048)];
            const f16x8 b2 = *(const f16x8*)&lds[rbase + (((3*h+2)*2 + nt) * 2048)];
            // A prefetch: tile t+1, frag ph (k16 = ph>>1, arr = ph&1)
            if (t < 7)
                aS[(t + 1) & 1][ph] = *(const f16x8*)
                    (wsb + offAb[h] + (unsigned)((t + 1) * 4096 + k16 * 1024));
            if (ph == 7) {
                if (t < 6) {
#pragma unroll
                    for (int c = 0; c < 6; ++c)
                        dma16(wsb + goffW[c] + (unsigned)((t + 2) * 4096),
                              &lds[nxtw * SLABF + ldstW[c]]);
                    asm volatile("s_waitcnt vmcnt(6)" ::: "memory");
                } else if (t == 6) {
                    asm volatile("s_waitcnt vmcnt(0)" ::: "memory");
                }
            }
            __builtin_amdgcn_s_barrier();
            asm volatile("s_waitcnt lgkmcnt(0)" ::: "memory");
            __builtin_amdgcn_s_setprio(1);
            const int cid2 = h ? 3 : 2;
            acc[0]    = __builtin_amdgcn_mfma_f32_32x32x16_f16(
                            aS[t & 1][ph], b0, acc[0], 0, 0, 0);
            acc[1]    = __builtin_amdgcn_mfma_f32_32x32x16_f16(
                            aS[t & 1][ph], b1, acc[1], 0, 0, 0);
            acc[cid2] = __builtin_amdgcn_mfma_f32_32x32x16_f16(
                            aS[t & 1][ph], b2, acc[cid2], 0, 0, 0);
            __builtin_amdgcn_s_setprio(0);
            __builtin_amdgcn_s_barrier();
        }
    }

    constexpr float S14 = 16384.0f,     I14 = 1.0f / 16384.0f;
    constexpr float S15 = 32768.0f,     I15 = 1.0f / 32768.0f;

    const int lh = lane >> 5, l32 = lane & 31;
    const int n = n0 + nt * 32 + l32;
    const float brc = bih[n] + bhh[n];                 // merged r bias
    const float bic = bih[n + 512] + bhh[n + 512];     // merged i bias
    const float bnn = bih[n + 1024];
    const float cnn = bhh[n + 1024];

#pragma unroll
    for (int r = 0; r < 16; ++r) {
        const int row = (r & 3) + 8 * (r >> 2) + 4 * lh;
        const int m   = m0 + mt * 32 + row;
        const float hv = hid[(size_t)m * Hsz + n];
        const float rg  = qsigmoid_dev(qround(acc[0][r] + brc, S14, I14));
        const float ig  = qsigmoid_dev(qround(acc[1][r] + bic, S14, I14));
        const float gin = qround(acc[2][r] + bnn, S14, I14);
        const float ghn = qround(acc[3][r] + cnn, S14, I14);
        const float rh  = qround(rg * ghn, S15, I15);
        const float ng  = qtanh_dev(rh + gin);
        const float nh  = qround(hv, S15, I15);
        out[(size_t)m * Hsz + n] = ng + ig * (nh - ng);
    }
}

// ---------------- fallback: bf16x3 (used only if ws too small) -------------
__global__ __launch_bounds__(256, 2) void qgru_mfma_bf16x3(
    const float* __restrict__ x, const float* __restrict__ hid,
    const float* __restrict__ wih, const float* __restrict__ whh,
    const float* __restrict__ bih, const float* __restrict__ bhh,
    float* __restrict__ out)
{
    __shared__ __align__(16) unsigned short lds[16384];

    const int t = threadIdx.x, lane = t & 63, wid = t >> 6;
    const int mt = wid >> 1, nt = wid & 1;
    const int m0 = blockIdx.x * BM, n0 = blockIdx.y * BN;
    const int s_r = t >> 2, s_k = (t & 3) << 2;
    const int s_kh = s_k >> 3, s_j = s_k & 7, s_rt = s_r >> 5, s_r32 = s_r & 31;

    const float* gA[2];
    gA[0] = x   + (size_t)(m0 + s_r) * Ksz + s_k;
    gA[1] = hid + (size_t)(m0 + s_r) * Ksz + s_k;
    const float* gW[6];
#pragma unroll
    for (int g = 0; g < 3; ++g) {
        gW[g]     = wih + (size_t)(g * Hsz + n0 + s_r) * Ksz + s_k;
        gW[g + 3] = whh + (size_t)(g * Hsz + n0 + s_r) * Ksz + s_k;
    }
    const int lh = lane >> 5, l32 = lane & 31;

    f32x16 acc[6];
#pragma unroll
    for (int g = 0; g < 6; ++g)
#pragma unroll
        for (int i = 0; i < 16; ++i) acc[g][i] = 0.0f;

    float4 vA[2], vW[6];
#pragma unroll
    for (int tt = 0; tt < 2; ++tt) vA[tt] = *(const float4*)gA[tt];
#pragma unroll
    for (int g = 0; g < 6; ++g)    vW[g]  = *(const float4*)gW[g];

    for (int k0 = 0; k0 < Ksz; k0 += 16) {
        __syncthreads();
#pragma unroll
        for (int tt = 0; tt < 2; ++tt) {
            unsigned h0, h1, l0, l1;
            split2(vA[tt].x, vA[tt].y, h0, l0);
            split2(vA[tt].z, vA[tt].w, h1, l1);
            unsigned bH = ((((tt*2+0)*2+s_rt)*2+s_kh)*32+s_r32)*8 + s_j;
            unsigned bL = ((((tt*2+1)*2+s_rt)*2+s_kh)*32+s_r32)*8 + s_j;
            *reinterpret_cast<uint2*>(&lds[bH]) = make_uint2(h0, h1);
            *reinterpret_cast<uint2*>(&lds[bL]) = make_uint2(l0, l1);
        }
#pragma unroll
        for (int g = 0; g < 6; ++g) {
            unsigned h0, h1, l0, l1;
            split2(vW[g].x, vW[g].y, h0, l0);
            split2(vW[g].z, vW[g].w, h1, l1);
            unsigned bH = 4096u + ((((g*2+0)*2+s_rt)*2+s_kh)*32+s_r32)*8 + s_j;
            unsigned bL = 4096u + ((((g*2+1)*2+s_rt)*2+s_kh)*32+s_r32)*8 + s_j;
            *reinterpret_cast<uint2*>(&lds[bH]) = make_uint2(h0, h1);
            *reinterpret_cast<uint2*>(&lds[bL]) = make_uint2(l0, l1);
        }
        __syncthreads();
        const int kn = (k0 + 16 < Ksz) ? (k0 + 16) : 0;
#pragma unroll
        for (int tt = 0; tt < 2; ++tt) vA[tt] = *(const float4*)(gA[tt] + kn);
#pragma unroll
        for (int g = 0; g < 6; ++g)    vW[g]  = *(const float4*)(gW[g] + kn);

        const bf16x8 ax_hi = *reinterpret_cast<const bf16x8*>(&lds[((((0)*2+mt)*2+lh)*32+l32)*8]);
        const bf16x8 ax_lo = *reinterpret_cast<const bf16x8*>(&lds[((((1)*2+mt)*2+lh)*32+l32)*8]);
        const bf16x8 ah_hi = *reinterpret_cast<const bf16x8*>(&lds[((((2)*2+mt)*2+lh)*32+l32)*8]);
        const bf16x8 ah_lo = *reinterpret_cast<const bf16x8*>(&lds[((((3)*2+mt)*2+lh)*32+l32)*8]);
#pragma unroll
        for (int g = 0; g < 6; ++g) {
            const bf16x8 b_hi = *reinterpret_cast<const bf16x8*>(&lds[4096u + ((((g*2+0)*2+nt)*2+lh)*32+l32)*8]);
            const bf16x8 b_lo = *reinterpret_cast<const bf16x8*>(&lds[4096u + ((((g*2+1)*2+nt)*2+lh)*32+l32)*8]);
            const bf16x8 a_hi = (g < 3) ? ax_hi : ah_hi;
            const bf16x8 a_lo = (g < 3) ? ax_lo : ah_lo;
            acc[g] = __builtin_amdgcn_mfma_f32_32x32x16_bf16(a_hi, b_hi, acc[g], 0, 0, 0);
            acc[g] = __builtin_amdgcn_mfma_f32_32x32x16_bf16(a_hi, b_lo, acc[g], 0, 0, 0);
            acc[g] = __builtin_amdgcn_mfma_f32_32x32x16_bf16(a_lo, b_hi, acc[g], 0, 0, 0);
        }
    }

    constexpr float S14 = 16384.0f,     I14 = 1.0f / 16384.0f;
    constexpr float S15 = 32768.0f,     I15 = 1.0f / 32768.0f;
    constexpr float S27 = 134217728.0f, I27 = 1.0f / 134217728.0f;
    const int n = n0 + nt * 32 + l32;
    const float br = bih[n], bi = bih[n + 512], bn = bih[n + 1024];
    const float cr = bhh[n], ci = bhh[n + 512], cn = bhh[n + 1024];
#pragma unroll
    for (int r = 0; r < 16; ++r) {
        const int row = (r & 3) + 8 * (r >> 2) + 4 * lh;
        const int m   = m0 + mt * 32 + row;
        const float hv = hid[(size_t)m * Hsz + n];
        float gir = qround(acc[0][r] + br, S14, I14);
        float gii = qround(acc[1][r] + bi, S14, I14);
        float gin = qround(acc[2][r] + bn, S14, I14);
        float ghr = qround(acc[3][r] + cr, S14, I14);
        float ghi = qround(acc[4][r] + ci, S14, I14);
        float ghn = qround(acc[5][r] + cn, S14, I14);
        float resetg = qsigmoid_dev(gir + ghr);
        float inputg = qsigmoid_dev(gii + ghi);
        float hn  = qround(ghn, S27, I27);
        float rh  = qround(resetg * hn, S15, I15);
        float newg = qtanh_dev(rh + gin);
        float nh  = qround(hv, S15, I15);
        out[(size_t)m * Hsz + n] = newg + inputg * (nh - newg);
    }
}

extern "C" void kernel_launch(void* const* d_in, const int* in_sizes, int n_in,
                              void* d_out, int out_size, void* d_ws, size_t ws_size,
                              hipStream_t stream) {
    const float* x   = (const float*)d_in[0];
    const float* hid = (const float*)d_in[1];
    const float* wih = (const float*)d_in[2];
    const float* whh = (const float*)d_in[3];
    const float* bih = (const float*)d_in[4];
    const float* bhh = (const float*)d_in[5];
    float* out = (float*)d_out;

    if (ws_size >= WS_NEED) {
        cvt_lds_f16<<<1216, 256, 0, stream>>>(
            x, hid, wih, whh, (_Float16*)d_ws);
        qgru_f16_p8<<<512, 512, 0, stream>>>(
            (const _Float16*)d_ws, hid, bih, bhh, out);
    } else {
        dim3 grid(Bsz / BM, Hsz / BN);
        qgru_mfma_bf16x3<<<grid, dim3(256), 0, stream>>>(
            x, hid, wih, whh, bih, bhh, out);
    }
}

// Round 7
// 129.850 us; speedup vs baseline: 1.0354x; 1.0327x over previous
//
#include <hip/hip_runtime.h>
#include <math.h>

// QGRUCell — Round 13: occupancy A/B. R7's proven kernel (44.9us) with
// K-step 32->16 so dbuf LDS drops 64KB->32KB => 4 blocks/CU co-resident
// (16 waves/CU, was 8). Six schedule rewrites (2-phase/A-reg/deep-prefetch/
// low-dup/8-phase) all pinned at 43-50us with per-CU delivery ~6B/cyc and
// Occupancy ~18% — latency x concurrency limit; this tests TLP as the fix.
// Everything else (ws layout, syncthreads-drain staging, epilogue numerics)
// is R7-verbatim. ws: 512-f16 chunks, A: arr*8192+M32*32+K16,
// W: 16384+(g*16+N32)*32+K16; chunk pos(row,k)=(k>>3&1)*256+row*8+(k&7).

typedef _Float16 f16x8  __attribute__((ext_vector_type(8)));
typedef _Float16 f16x4  __attribute__((ext_vector_type(4)));
typedef __bf16   bf16x8 __attribute__((ext_vector_type(8)));
typedef float    f32x16 __attribute__((ext_vector_type(16)));

namespace {

constexpr int Bsz = 8192, Ksz = 512, Hsz = 512;
constexpr int BM = 64, BN = 64;

constexpr unsigned WCH0    = 16384u;
constexpr unsigned NCHUNK  = 16384u + 3072u;          // 19456
constexpr unsigned WS_F16  = NCHUNK * 512u;           // 9,961,472 f16
constexpr size_t   WS_NEED = (size_t)WS_F16 * 2;      // 19,922,944 B

__device__ __forceinline__ float qround(float x, float s, float invs) {
    return floorf(x * s + 0.5f) * invs;
}

__device__ __forceinline__ float qsigmoid_dev(float x) {
    float iq = floorf(x * 134217728.0f + 0.5f);
    iq = fminf(fmaxf(iq, -2147483648.0f), 2147483648.0f);
    float e = __expf(-iq * 7.450580596923828125e-9f);
    float s = __builtin_amdgcn_rcpf(1.0f + e);
    float q31 = floorf(s * 2147483648.0f + 0.5f);
    float q15 = floorf(q31 * 1.52587890625e-5f + 0.5f);
    return q15 * 3.0517578125e-5f;
}

__device__ __forceinline__ float qtanh_dev(float x) {
    float iq = floorf(x * 134217728.0f + 0.5f);
    iq = fminf(fmaxf(iq, -2147483648.0f), 2147483648.0f);
    float z = iq * 7.450580596923828125e-9f;
    float e = __expf(2.0f * z);
    float t = 1.0f - 2.0f * __builtin_amdgcn_rcpf(e + 1.0f);
    float q31 = floorf(t * 2147483648.0f + 0.5f);
    float q15 = floorf(q31 * 1.52587890625e-5f + 0.5f);
    return q15 * 3.0517578125e-5f;
}

__device__ __forceinline__ void dma16(const void* g, void* l) {
    __builtin_amdgcn_global_load_lds(
        (const __attribute__((address_space(1))) unsigned int*)g,
        (__attribute__((address_space(3))) unsigned int*)l, 16, 0, 0);
}

__device__ __forceinline__ void split2(float a, float b, unsigned& hi, unsigned& lo) {
    unsigned ua = __float_as_uint(a); ua += 0x7fffu + ((ua >> 16) & 1u);
    unsigned ub = __float_as_uint(b); ub += 0x7fffu + ((ub >> 16) & 1u);
    hi = (ua >> 16) | (ub & 0xffff0000u);
    float ra = a - __uint_as_float(ua & 0xffff0000u);
    float rb = b - __uint_as_float(ub & 0xffff0000u);
    unsigned va = __float_as_uint(ra); va += 0x7fffu + ((va >> 16) & 1u);
    unsigned vb = __float_as_uint(rb); vb += 0x7fffu + ((vb >> 16) & 1u);
    lo = (va >> 16) | (vb & 0xffff0000u);
}

} // namespace

// ---------------- pre-pass: LDS-tile-transpose fp32 -> f16 chunks ----------
__global__ __launch_bounds__(256) void cvt_lds_f16(
    const float* __restrict__ x, const float* __restrict__ h,
    const float* __restrict__ wih, const float* __restrict__ whh,
    _Float16* __restrict__ ws)
{
    __shared__ __align__(16) _Float16 lt[8192];   // 16 KB

    const int b2  = blockIdx.x;
    const int b   = b2 >> 1;
    const int kha = b2 & 1;
    const int tid = threadIdx.x;

    const float* src;      // base of the 32-row group (row-major, stride 512)
    unsigned chbase;       // first chunk index of this group
    if (b < 512) {                         // A: x (arr0), h (arr1)
        const int arr = b >> 8, M32 = b & 255;
        src = (arr ? h : x) + (size_t)M32 * 32u * 512u;
        chbase = (unsigned)arr * 8192u + (unsigned)M32 * 32u;
    } else {                               // W: gate g, col-group N32
        const int w = b - 512;             // 0..95
        const int g = w >> 4, N32 = w & 15;
        const int rowLocal = (g % 3) * 512 + N32 * 32;
        src = (g < 3 ? wih : whh) + (size_t)rowLocal * 512u;
        chbase = WCH0 + (unsigned)((g * 16 + N32) * 32);
    }
    src += kha * 256;                      // K-half column offset

    // Phase 1: 8 reps x 256 threads covering 32 rows x 64 float4s
#pragma unroll
    for (int rep = 0; rep < 8; ++rep) {
        const int idx = rep * 256 + tid;       // 0..2047
        const int row = idx >> 6;              // 0..31
        const int q   = idx & 63;              // local float4 col
        const float4 v = *(const float4*)(src + (size_t)row * 512 + q * 4);
        const int K16l = q >> 2;               // 0..15
        const int kh   = (q >> 1) & 1;
        const int half = (q & 1) * 4;
        const int rsw  = (row + (q >> 1)) & 31;
        f16x4 o;
        o[0] = (_Float16)v.x; o[1] = (_Float16)v.y;
        o[2] = (_Float16)v.z; o[3] = (_Float16)v.w;
        *(f16x4*)&lt[K16l * 512 + kh * 256 + rsw * 8 + half] = o;
    }
    __syncthreads();

    // Phase 2: wave w writes chunks K16l = w*4 .. w*4+3
    const int wid = tid >> 6, lane = tid & 63;
    const int kh  = lane >> 5, row = lane & 31;
#pragma unroll
    for (int cc = 0; cc < 4; ++cc) {
        const int K16l = wid * 4 + cc;
        const int rsw  = (row + 2 * K16l + kh) & 31;
        const f16x8 o = *(const f16x8*)&lt[K16l * 512 + kh * 256 + rsw * 8];
        *(f16x8*)(ws + (size_t)(chbase + (unsigned)(kha * 16 + K16l)) * 512u
                      + lane * 8) = o;
    }
}

// ---------------- main: R7 structure, KT=16, 32KB LDS, 4 blocks/CU ---------
__global__ __launch_bounds__(256, 4) void qgru_f16_occ(
    const _Float16* __restrict__ ws, const float* __restrict__ hid,
    const float* __restrict__ bih, const float* __restrict__ bhh,
    float* __restrict__ out)
{
    __shared__ __align__(16) _Float16 lds[16384];   // 32 KB (2 slabs x 16 KB)

    const int t = threadIdx.x, lane = t & 63, wid = t >> 6;
    const int mt = wid >> 1, nt = wid & 1;
    const int m0 = blockIdx.x * BM, n0 = blockIdx.y * BN;

    // 16 chunks per step (one K16 slice): idx 0..3 = A (arr, mtc),
    // idx 4..15 = W (g, ntc). Wave wid stages idx = wid*4 .. wid*4+3.
    unsigned goff[4];
    int      ldst[4];
#pragma unroll
    for (int c = 0; c < 4; ++c) {
        const int idx = wid * 4 + c;
        unsigned ch; int lo;
        if (idx < 4) {
            const int arr = idx >> 1, mtc = idx & 1;
            ch = (unsigned)arr * 8192u + (unsigned)((m0 >> 5) + mtc) * 32u;
            lo = idx * 512;
        } else {
            const int w = idx - 4, g = w >> 1, ntc = w & 1;
            ch = WCH0 + (unsigned)((g * 16 + (n0 >> 5) + ntc) * 32);
            lo = 2048 + w * 512;
        }
        goff[c] = ch * 1024u + (unsigned)lane * 16u;
        ldst[c] = lo;
    }

    f32x16 acc[6];
#pragma unroll
    for (int g = 0; g < 6; ++g)
#pragma unroll
        for (int i = 0; i < 16; ++i) acc[g][i] = 0.0f;

    const char* wsb = (const char*)ws;
    const int lr = lane & 31, lk8 = (lane >> 5) * 8;

#pragma unroll
    for (int c = 0; c < 4; ++c)
        dma16(wsb + goff[c], &lds[ldst[c]]);

    for (int step = 0; step < 32; ++step) {
        __syncthreads();                       // implicit vmcnt(0) drain

        if (step + 1 < 32) {
            const unsigned kb = (unsigned)(step + 1) * 1024u;
            const int nb = ((step + 1) & 1) * 8192;
#pragma unroll
            for (int c = 0; c < 4; ++c)
                dma16(wsb + goff[c] + kb, &lds[nb + ldst[c]]);
        }

        const int cb = (step & 1) * 8192;
        const int lfo = cb + lk8 * 32 + lr * 8;
        const f16x8 ax = *(const f16x8*)&lds[lfo + (0 + mt) * 512];
        const f16x8 ah = *(const f16x8*)&lds[lfo + (2 + mt) * 512];
#pragma unroll
        for (int g = 0; g < 6; ++g) {
            const f16x8 b = *(const f16x8*)&lds[lfo + 2048 + (g * 2 + nt) * 512];
            acc[g] = __builtin_amdgcn_mfma_f32_32x32x16_f16(
                         g < 3 ? ax : ah, b, acc[g], 0, 0, 0);
        }
    }

    constexpr float S14 = 16384.0f,     I14 = 1.0f / 16384.0f;
    constexpr float S15 = 32768.0f,     I15 = 1.0f / 32768.0f;
    constexpr float S27 = 134217728.0f, I27 = 1.0f / 134217728.0f;

    const int lh = lane >> 5, l32 = lane & 31;
    const int n = n0 + nt * 32 + l32;
    const float br = bih[n], bi = bih[n + 512], bn = bih[n + 1024];
    const float cr = bhh[n], ci = bhh[n + 512], cn = bhh[n + 1024];

#pragma unroll
    for (int r = 0; r < 16; ++r) {
        const int row = (r & 3) + 8 * (r >> 2) + 4 * lh;
        const int m   = m0 + mt * 32 + row;
        const float hv = hid[(size_t)m * Hsz + n];

        float gir = qround(acc[0][r] + br, S14, I14);
        float gii = qround(acc[1][r] + bi, S14, I14);
        float gin = qround(acc[2][r] + bn, S14, I14);
        float ghr = qround(acc[3][r] + cr, S14, I14);
        float ghi = qround(acc[4][r] + ci, S14, I14);
        float ghn = qround(acc[5][r] + cn, S14, I14);
        float resetg = qsigmoid_dev(gir + ghr);
        float inputg = qsigmoid_dev(gii + ghi);
        float hn  = qround(ghn, S27, I27);
        float rh  = qround(resetg * hn, S15, I15);
        float newg = qtanh_dev(rh + gin);
        float nh  = qround(hv, S15, I15);
        out[(size_t)m * Hsz + n] = newg + inputg * (nh - newg);
    }
}

// ---------------- fallback: bf16x3 (used only if ws too small) -------------
__global__ __launch_bounds__(256, 2) void qgru_mfma_bf16x3(
    const float* __restrict__ x, const float* __restrict__ hid,
    const float* __restrict__ wih, const float* __restrict__ whh,
    const float* __restrict__ bih, const float* __restrict__ bhh,
    float* __restrict__ out)
{
    __shared__ __align__(16) unsigned short lds[16384];

    const int t = threadIdx.x, lane = t & 63, wid = t >> 6;
    const int mt = wid >> 1, nt = wid & 1;
    const int m0 = blockIdx.x * BM, n0 = blockIdx.y * BN;
    const int s_r = t >> 2, s_k = (t & 3) << 2;
    const int s_kh = s_k >> 3, s_j = s_k & 7, s_rt = s_r >> 5, s_r32 = s_r & 31;

    const float* gA[2];
    gA[0] = x   + (size_t)(m0 + s_r) * Ksz + s_k;
    gA[1] = hid + (size_t)(m0 + s_r) * Ksz + s_k;
    const float* gW[6];
#pragma unroll
    for (int g = 0; g < 3; ++g) {
        gW[g]     = wih + (size_t)(g * Hsz + n0 + s_r) * Ksz + s_k;
        gW[g + 3] = whh + (size_t)(g * Hsz + n0 + s_r) * Ksz + s_k;
    }
    const int lh = lane >> 5, l32 = lane & 31;

    f32x16 acc[6];
#pragma unroll
    for (int g = 0; g < 6; ++g)
#pragma unroll
        for (int i = 0; i < 16; ++i) acc[g][i] = 0.0f;

    float4 vA[2], vW[6];
#pragma unroll
    for (int tt = 0; tt < 2; ++tt) vA[tt] = *(const float4*)gA[tt];
#pragma unroll
    for (int g = 0; g < 6; ++g)    vW[g]  = *(const float4*)gW[g];

    for (int k0 = 0; k0 < Ksz; k0 += 16) {
        __syncthreads();
#pragma unroll
        for (int tt = 0; tt < 2; ++tt) {
            unsigned h0, h1, l0, l1;
            split2(vA[tt].x, vA[tt].y, h0, l0);
            split2(vA[tt].z, vA[tt].w, h1, l1);
            unsigned bH = ((((tt*2+0)*2+s_rt)*2+s_kh)*32+s_r32)*8 + s_j;
            unsigned bL = ((((tt*2+1)*2+s_rt)*2+s_kh)*32+s_r32)*8 + s_j;
            *reinterpret_cast<uint2*>(&lds[bH]) = make_uint2(h0, h1);
            *reinterpret_cast<uint2*>(&lds[bL]) = make_uint2(l0, l1);
        }
#pragma unroll
        for (int g = 0; g < 6; ++g) {
            unsigned h0, h1, l0, l1;
            split2(vW[g].x, vW[g].y, h0, l0);
            split2(vW[g].z, vW[g].w, h1, l1);
            unsigned bH = 4096u + ((((g*2+0)*2+s_rt)*2+s_kh)*32+s_r32)*8 + s_j;
            unsigned bL = 4096u + ((((g*2+1)*2+s_rt)*2+s_kh)*32+s_r32)*8 + s_j;
            *reinterpret_cast<uint2*>(&lds[bH]) = make_uint2(h0, h1);
            *reinterpret_cast<uint2*>(&lds[bL]) = make_uint2(l0, l1);
        }
        __syncthreads();
        const int kn = (k0 + 16 < Ksz) ? (k0 + 16) : 0;
#pragma unroll
        for (int tt = 0; tt < 2; ++tt) vA[tt] = *(const float4*)(gA[tt] + kn);
#pragma unroll
        for (int g = 0; g < 6; ++g)    vW[g]  = *(const float4*)(gW[g] + kn);

        const bf16x8 ax_hi = *reinterpret_cast<const bf16x8*>(&lds[((((0)*2+mt)*2+lh)*32+l32)*8]);
        const bf16x8 ax_lo = *reinterpret_cast<const bf16x8*>(&lds[((((1)*2+mt)*2+lh)*32+l32)*8]);
        const bf16x8 ah_hi = *reinterpret_cast<const bf16x8*>(&lds[((((2)*2+mt)*2+lh)*32+l32)*8]);
        const bf16x8 ah_lo = *reinterpret_cast<const bf16x8*>(&lds[((((3)*2+mt)*2+lh)*32+l32)*8]);
#pragma unroll
        for (int g = 0; g < 6; ++g) {
            const bf16x8 b_hi = *reinterpret_cast<const bf16x8*>(&lds[4096u + ((((g*2+0)*2+nt)*2+lh)*32+l32)*8]);
            const bf16x8 b_lo = *reinterpret_cast<const bf16x8*>(&lds[4096u + ((((g*2+1)*2+nt)*2+lh)*32+l32)*8]);
            const bf16x8 a_hi = (g < 3) ? ax_hi : ah_hi;
            const bf16x8 a_lo = (g < 3) ? ax_lo : ah_lo;
            acc[g] = __builtin_amdgcn_mfma_f32_32x32x16_bf16(a_hi, b_hi, acc[g], 0, 0, 0);
            acc[g] = __builtin_amdgcn_mfma_f32_32x32x16_bf16(a_hi, b_lo, acc[g], 0, 0, 0);
            acc[g] = __builtin_amdgcn_mfma_f32_32x32x16_bf16(a_lo, b_hi, acc[g], 0, 0, 0);
        }
    }

    constexpr float S14 = 16384.0f,     I14 = 1.0f / 16384.0f;
    constexpr float S15 = 32768.0f,     I15 = 1.0f / 32768.0f;
    constexpr float S27 = 134217728.0f, I27 = 1.0f / 134217728.0f;
    const int n = n0 + nt * 32 + l32;
    const float br = bih[n], bi = bih[n + 512], bn = bih[n + 1024];
    const float cr = bhh[n], ci = bhh[n + 512], cn = bhh[n + 1024];
#pragma unroll
    for (int r = 0; r < 16; ++r) {
        const int row = (r & 3) + 8 * (r >> 2) + 4 * lh;
        const int m   = m0 + mt * 32 + row;
        const float hv = hid[(size_t)m * Hsz + n];
        float gir = qround(acc[0][r] + br, S14, I14);
        float gii = qround(acc[1][r] + bi, S14, I14);
        float gin = qround(acc[2][r] + bn, S14, I14);
        float ghr = qround(acc[3][r] + cr, S14, I14);
        float ghi = qround(acc[4][r] + ci, S14, I14);
        float ghn = qround(acc[5][r] + cn, S14, I14);
        float resetg = qsigmoid_dev(gir + ghr);
        float inputg = qsigmoid_dev(gii + ghi);
        float hn  = qround(ghn, S27, I27);
        float rh  = qround(resetg * hn, S15, I15);
        float newg = qtanh_dev(rh + gin);
        float nh  = qround(hv, S15, I15);
        out[(size_t)m * Hsz + n] = newg + inputg * (nh - newg);
    }
}

extern "C" void kernel_launch(void* const* d_in, const int* in_sizes, int n_in,
                              void* d_out, int out_size, void* d_ws, size_t ws_size,
                              hipStream_t stream) {
    const float* x   = (const float*)d_in[0];
    const float* hid = (const float*)d_in[1];
    const float* wih = (const float*)d_in[2];
    const float* whh = (const float*)d_in[3];
    const float* bih = (const float*)d_in[4];
    const float* bhh = (const float*)d_in[5];
    float* out = (float*)d_out;
    dim3 grid(Bsz / BM, Hsz / BN);   // 128 x 8 = 1024 blocks = 4/CU

    if (ws_size >= WS_NEED) {
        cvt_lds_f16<<<1216, 256, 0, stream>>>(
            x, hid, wih, whh, (_Float16*)d_ws);
        qgru_f16_occ<<<grid, dim3(256), 0, stream>>>(
            (const _Float16*)d_ws, hid, bih, bhh, out);
    } else {
        qgru_mfma_bf16x3<<<grid, dim3(256), 0, stream>>>(
            x, hid, wih, whh, bih, bhh, out);
    }
}